// Round 8
// baseline (266.123 us; speedup 1.0000x reference)
//
#include <hip/hip_runtime.h>
#include <hip/hip_bf16.h>

typedef __attribute__((ext_vector_type(8))) short short8;
typedef __attribute__((ext_vector_type(4))) short s4v;
typedef __attribute__((ext_vector_type(4))) int   int4v;
typedef __attribute__((ext_vector_type(4))) float floatx4;

#define MFMA16(A,B,C) __builtin_amdgcn_mfma_f32_16x16x32_bf16(A,B,C,0,0,0)

__device__ __forceinline__ short bf16bits(float x) {
    __hip_bfloat16 h = __float2bfloat16(x);
    return *(short*)&h;
}
__device__ __forceinline__ short8 cvt8(const float* p) {
    floatx4 a = *(const floatx4*)p;
    floatx4 b = *(const floatx4*)(p + 4);
    short8 r;
    r[0]=bf16bits(a.x); r[1]=bf16bits(a.y); r[2]=bf16bits(a.z); r[3]=bf16bits(a.w);
    r[4]=bf16bits(b.x); r[5]=bf16bits(b.y); r[6]=bf16bits(b.z); r[7]=bf16bits(b.w);
    return r;
}
// scaled variant for Q: folds 1/sqrt(d) * log2(e) so softmax is a bare v_exp_f32
__device__ __forceinline__ short8 cvt8s(const float* p) {
    constexpr float SCL2 = 0.125f * 1.44269504088896f;
    floatx4 a = *(const floatx4*)p;
    floatx4 b = *(const floatx4*)(p + 4);
    a *= SCL2; b *= SCL2;
    short8 r;
    r[0]=bf16bits(a.x); r[1]=bf16bits(a.y); r[2]=bf16bits(a.z); r[3]=bf16bits(a.w);
    r[4]=bf16bits(b.x); r[5]=bf16bits(b.y); r[6]=bf16bits(b.z); r[7]=bf16bits(b.w);
    return r;
}
// hardware packed f32->bf16 (RNE, identical rounding to __float2bfloat16)
__device__ __forceinline__ int pk2(float lo, float hi) {
    int r;
    asm("v_cvt_pk_bf16_f32 %0, %1, %2" : "=v"(r) : "v"(lo), "v"(hi));
    return r;
}
// direct global->LDS DMA, 16B/lane; LDS dest = wave-uniform base + lane*16
__device__ __forceinline__ void g2l16(const short* g, short* l) {
    __builtin_amdgcn_global_load_lds(
        (const __attribute__((address_space(1))) void*)g,
        (__attribute__((address_space(3))) void*)l, 16, 0, 0);
}

// ---- prologue (fused): V -> VT [h][d][s] bf16, and K -> K16 bf16 row-major ----
__global__ __launch_bounds__(256) void prep(const float* __restrict__ V,
                                            short* __restrict__ VT,
                                            const float* __restrict__ K,
                                            short* __restrict__ K16, int doK)
{
    __shared__ short tile[64 * 65];
    const int t  = threadIdx.x;
    const int h  = blockIdx.x >> 6;
    const int s0 = (blockIdx.x & 63) << 6;
    const float* src = V + ((size_t)h * 4096 + s0) * 64;
    const int r = t >> 4, dq = (t & 15) * 4;
#pragma unroll
    for (int pass = 0; pass < 4; ++pass) {
        const int s = pass * 16 + r;
        floatx4 f = *(const floatx4*)(src + s * 64 + dq);
        short* w = tile + s * 65 + dq;
        w[0] = bf16bits(f.x); w[1] = bf16bits(f.y);
        w[2] = bf16bits(f.z); w[3] = bf16bits(f.w);
    }
    __syncthreads();
    const int d = t >> 2, sc = (t & 3) * 16;
    short8 a, b;
#pragma unroll
    for (int j = 0; j < 8; ++j) a[j] = tile[(sc + j) * 65 + d];
#pragma unroll
    for (int j = 0; j < 8; ++j) b[j] = tile[(sc + 8 + j) * 65 + d];
    short* dst = VT + ((size_t)h * 64 + d) * 4096 + s0 + sc;
    *(short8*)dst       = a;
    *(short8*)(dst + 8) = b;
    if (doK) {
        const size_t base = (size_t)blockIdx.x * 4096 + (size_t)t * 16;
        *(short8*)(K16 + base)     = cvt8(K + base);
        *(short8*)(K16 + base + 8) = cvt8(K + base + 8);
    }
}

// ---- main: R7 split-K structure + async double-buffer staging ----
// 4 waves = (qhalf x khalf); 32q/wave (2 groups of 16); khalf waves split each
// 64-key tile into 32-key halves (plain-exp split-K, merge = pure add).
// K/V staged by global_load_lds into buf^1 while computing buf (1 barrier per
// round; barrier's vmcnt drain only waits on DMAs issued a full round earlier).
// DMA writes are linear (swizzle pre-inverted on the global source, R3-verified
// decode); merge scratch reuses lK/lV -> LDS 32KB -> 5 blocks/CU.
template<bool KB16>
__global__ __attribute__((amdgpu_waves_per_eu(5, 5))) __launch_bounds__(256)
void attn_fast(const float* __restrict__ Qg, const float* __restrict__ Kg,
               const short* __restrict__ K16g, const short* __restrict__ VTg,
               float* __restrict__ Og)
{
    constexpr int S = 4096, D = 64;

    __shared__ __align__(16) short lK[8192];   // 2 x (64 keys x 64 d), swizzled
    __shared__ __align__(16) short lV[8192];   // 2 x (64 d x 64 keys), swizzled

    const int tid = threadIdx.x;
    const int wv  = tid >> 6;        // 0..3
    const int ln  = tid & 63;
    const int ll  = ln & 15;
    const int qd  = ln >> 4;
    const int qhalf = wv & 1;        // which 32 q-rows of the 64-q block tile
    const int khalf = wv >> 1;       // which 32-key half of each 64-key tile

    // balanced qblk mapping: per-CU sets {63-x, 32+x, 31-x, x}
    const int c = blockIdx.x & 255;
    const int s = blockIdx.x >> 8;
    const int h = c & 15;
    const int x = c >> 4;
    const int qblk = (s == 0) ? (63 - x) : (s == 1) ? (32 + x) : (s == 2) ? (31 - x) : x;
    const int qb   = qblk << 6;
    const int qrow = qb + (qhalf << 5);       // wave owns 32 q-rows

    const float* Qh  = Qg  + (size_t)h * S * D;
    const float* Kf  = Kg  + (size_t)h * S * D;
    const short* K16 = K16g + (size_t)h * S * D;
    const short* Vt  = VTg + (size_t)h * 64 * S;

    // Q fragments for both 16-row groups, pre-scaled
    short8 qA0, qA1, qB0, qB1;
    {
        const float* qp = Qh + (qrow + ll) * D + qd * 8;
        qA0 = cvt8s(qp);       qA1 = cvt8s(qp + 32);
        const float* qp2 = qp + 16 * D;
        qB0 = cvt8s(qp2);      qB1 = cvt8s(qp2 + 32);
    }

    floatx4 oA[4], oB[4], olA, olB;
#pragma unroll
    for (int dt = 0; dt < 4; ++dt) { oA[dt] = (floatx4){0.f,0.f,0.f,0.f}; oB[dt] = oA[dt]; }
    olA = (floatx4){0.f,0.f,0.f,0.f};
    olB = olA;

    short8 ones;
#pragma unroll
    for (int j = 0; j < 8; ++j) ones[j] = (short)0x3F80;  // bf16 1.0

    // ---- staging via global_load_lds: linear LDS dest, swizzle-inverted source.
    // wave w, instr j (0..1) covers LDS short8-slots [(w*2+j)*64, +64), lane ln
    // -> slot+ln. Decode (HW-verified R3): hh=slot>>8, bb=(slot>>6)&3, sw=slot&63,
    //   ko=(sw>>4)&3; kkey=hh*32+(bb>>1)*16+((sw^(ko*5))&15); kd8=((bb&1)<<2)|ko
    //   vd=bb*16+((sw^(ko*5))&15); vOff=vd*S+hh*32+ko*8
    int kOff0, kOff1, vOff0, vOff1;
    const float *kFp0, *kFp1;              // fp32 K source (KB16=false path)
#define DECODE_SLOT(J, KOF, VOF, KFP) {                                        \
        const int slot = (wv * 2 + (J)) * 64 + ln;                             \
        const int hh = slot >> 8, bb = (slot >> 6) & 3, sw = slot & 63;        \
        const int ko = (sw >> 4) & 3;                                          \
        const int kkey = hh * 32 + (bb >> 1) * 16 + ((sw ^ (ko * 5)) & 15);    \
        const int kd8  = ((bb & 1) << 2) | ko;                                 \
        const int vd   = bb * 16 + ((sw ^ (ko * 5)) & 15);                     \
        KOF = kkey * 64 + kd8 * 8;                                             \
        VOF = vd * S + hh * 32 + ko * 8;                                       \
        KFP = Kf + (size_t)kkey * D + kd8 * 8;                                 \
    }
    DECODE_SLOT(0, kOff0, vOff0, kFp0)
    DECODE_SLOT(1, kOff1, vOff1, kFp1)
#undef DECODE_SLOT
    const int dstA = (wv * 2 + 0) * 512;   // short offset of this wave's chunk 0
    const int dstB = (wv * 2 + 1) * 512;   // chunk 1

    // fragment read block (lK / lV)
    const int rblk = ((ll | (qd << 4)) ^ (qd * 5));

    const int kv_end = qb + 64;          // keys needed by the 64-q block tile
    const int wv_end = qrow + 32;        // this wave's causal limit

    // softmax + in-register P->A-fragment transpose (HW-verified R4):
    // P32(w0,w2), P32(w1,w3), P16(w0,w2), P16(w1,w3)
    auto mkpf = [&](floatx4 sc0, floatx4 sc1, int qgrp, int kvh) -> short8 {
        float p0[4], p1[4];
#pragma unroll
        for (int r = 0; r < 4; ++r) { p0[r] = exp2f(sc0[r]); p1[r] = exp2f(sc1[r]); }
        if (kvh + 31 > qgrp) {                 // diagonal tiles only
            const int qg = qgrp + ll;
            const int k0 = kvh + qd * 4, k1 = k0 + 16;
#pragma unroll
            for (int r = 0; r < 4; ++r) {
                if (k0 + r > qg) p0[r] = 0.f;
                if (k1 + r > qg) p1[r] = 0.f;
            }
        }
        int w0 = pk2(p0[0], p0[1]);
        int w1 = pk2(p0[2], p0[3]);
        int w2 = pk2(p1[0], p1[1]);
        int w3 = pk2(p1[2], p1[3]);
        asm("v_permlane32_swap_b32 %0, %1" : "+v"(w0), "+v"(w2));
        asm("v_permlane32_swap_b32 %0, %1" : "+v"(w1), "+v"(w3));
        asm("v_permlane16_swap_b32 %0, %1" : "+v"(w0), "+v"(w2));
        asm("v_permlane16_swap_b32 %0, %1" : "+v"(w1), "+v"(w3));
        int4v pv = {w0, w1, w2, w3};
        return *(short8*)&pv;
    };

    // ---- prologue: stage tile 0 into buffer 0
    short8 kApre, kBpre;                   // false-path prefetch regs only
    g2l16(Vt + vOff0, lV + dstA);
    g2l16(Vt + vOff1, lV + dstB);
    if constexpr (KB16) {
        g2l16(K16 + kOff0, lK + dstA);
        g2l16(K16 + kOff1, lK + dstB);
    } else {
        *(short8*)(lK + dstA + ln * 8) = cvt8(kFp0);
        *(short8*)(lK + dstB + ln * 8) = cvt8(kFp1);
        if (64 < kv_end) {
            kApre = cvt8(kFp0 + (size_t)64 * D);
            kBpre = cvt8(kFp1 + (size_t)64 * D);
        }
    }

    int bo = 0;
    for (int kv = 0; kv < kv_end; kv += 64) {
        // single barrier: drains this wave's prior DMAs (vmcnt) + syncs block
        __syncthreads();
        const int nbo = bo ^ 4096;
        if (kv + 64 < kv_end) {            // stage next tile into other buffer
            const short* Vs = Vt + (kv + 64);
            g2l16(Vs + vOff0, lV + nbo + dstA);
            g2l16(Vs + vOff1, lV + nbo + dstB);
            if constexpr (KB16) {
                const short* Ks = K16 + (size_t)(kv + 64) * 64;
                g2l16(Ks + kOff0, lK + nbo + dstA);
                g2l16(Ks + kOff1, lK + nbo + dstB);
            } else {
                *(short8*)(lK + nbo + dstA + ln * 8) = kApre;
                *(short8*)(lK + nbo + dstB + ln * 8) = kBpre;
                if (kv + 128 < kv_end) {
                    kApre = cvt8(kFp0 + (size_t)(kv + 128) * D);
                    kBpre = cvt8(kFp1 + (size_t)(kv + 128) * D);
                }
            }
        }

        const int kvw = kv + (khalf << 5);    // this wave's 32-key half
        if (kvw < wv_end) {
            const short* Kb = lK + bo + (khalf << 11);
            const short* Vb = lV + bo + (khalf << 11);
            // S^T = K Q^T; each kf feeds both q-groups (2x reuse)
            floatx4 zz = (floatx4){0.f,0.f,0.f,0.f};
            floatx4 sA0=zz, sA1=zz, sB0=zz, sB1=zz;
            short8 kf;
            __builtin_amdgcn_s_setprio(1);
            kf = ((const short8*)(Kb +    0))[rblk]; sA0 = MFMA16(kf, qA0, sA0); sB0 = MFMA16(kf, qB0, sB0);
            kf = ((const short8*)(Kb +  512))[rblk]; sA0 = MFMA16(kf, qA1, sA0); sB0 = MFMA16(kf, qB1, sB0);
            kf = ((const short8*)(Kb + 1024))[rblk]; sA1 = MFMA16(kf, qA0, sA1); sB1 = MFMA16(kf, qB0, sB1);
            kf = ((const short8*)(Kb + 1536))[rblk]; sA1 = MFMA16(kf, qA1, sA1); sB1 = MFMA16(kf, qB1, sB1);
            __builtin_amdgcn_s_setprio(0);

            // softmax -> in-reg P fragments (32 keys each) -> PV
            short8 pfA = mkpf(sA0, sA1, qrow,      kvw);
            short8 pfB = mkpf(sB0, sB1, qrow + 16, kvw);
            __builtin_amdgcn_s_setprio(1);
#pragma unroll
            for (int dt = 0; dt < 4; ++dt) {
                short8 vf = ((const short8*)(Vb + dt * 512))[rblk];
                oA[dt] = MFMA16(pfA, vf, oA[dt]);
                oB[dt] = MFMA16(pfB, vf, oB[dt]);
            }
            olA = MFMA16(pfA, ones, olA);
            olB = MFMA16(pfB, ones, olB);
            __builtin_amdgcn_s_setprio(0);
        }
        bo = nbo;
    }

    // ---- split-K merge: plain-exp softmax => pure addition of O and row-sums.
    // khalf=1 waves publish partials via lK/lV scratch; khalf=0 combine + store.
    __syncthreads();
    float* sAod = (float*)lK;            // 2 x 64 lanes x 20 floats = 10 KB
    float* sBod = (float*)lV;
    const int mbase = ((qhalf << 6) + ln) * 20;
    if (khalf == 1) {
#pragma unroll
        for (int dt = 0; dt < 4; ++dt)
#pragma unroll
            for (int r = 0; r < 4; ++r) {
                sAod[mbase + dt * 4 + r] = oA[dt][r];
                sBod[mbase + dt * 4 + r] = oB[dt][r];
            }
#pragma unroll
        for (int r = 0; r < 4; ++r) {
            sAod[mbase + 16 + r] = olA[r];
            sBod[mbase + 16 + r] = olB[r];
        }
    }
    __syncthreads();
    if (khalf == 0) {
#pragma unroll
        for (int dt = 0; dt < 4; ++dt)
#pragma unroll
            for (int r = 0; r < 4; ++r) {
                oA[dt][r] += sAod[mbase + dt * 4 + r];
                oB[dt][r] += sBod[mbase + dt * 4 + r];
            }
#pragma unroll
        for (int r = 0; r < 4; ++r) {
            olA[r] += sAod[mbase + 16 + r];
            olB[r] += sBod[mbase + 16 + r];
        }
#pragma unroll
        for (int r = 0; r < 4; ++r) {
            const float rl = 1.f / fmaxf(olA[r], 1e-37f);
            const int q = qrow + qd * 4 + r;
            float* op = Og + ((size_t)h * S + q) * D + ll;
#pragma unroll
            for (int dt = 0; dt < 4; ++dt)
                op[dt * 16] = oA[dt][r] * rl;
        }
#pragma unroll
        for (int r = 0; r < 4; ++r) {
            const float rl = 1.f / fmaxf(olB[r], 1e-37f);
            const int q = qrow + 16 + qd * 4 + r;
            float* op = Og + ((size_t)h * S + q) * D + ll;
#pragma unroll
            for (int dt = 0; dt < 4; ++dt)
                op[dt * 16] = oB[dt][r] * rl;
        }
    }
}

// ---- fallback (round-3 verified kernel, no workspace needed) ----
__global__ __launch_bounds__(256, 4)
void attn_legacy(const float* __restrict__ Qg, const float* __restrict__ Kg,
                 const float* __restrict__ Vg, float* __restrict__ Og)
{
    constexpr int S = 4096, D = 64;
    constexpr float SCL2 = 0.125f * 1.44269504088896f;
    constexpr float NEG  = -1.0e30f;
    __shared__ __align__(16) short lK[2048];
    __shared__ __align__(16) short lV[2048];
    __shared__ __align__(16) short lP[2048];
    const int tid = threadIdx.x, wv = tid >> 6, ln = tid & 63, ll = ln & 15, qd = ln >> 4;
    const int bid = blockIdx.x, h = bid & 15, qblk = 63 - (bid >> 4), qb = qblk << 6;
    const float* Qh = Qg + (size_t)h * S * D;
    const float* Kh = Kg + (size_t)h * S * D;
    const float* Vh = Vg + (size_t)h * S * D;
    const int qrow = qb + wv * 16;
    short8 qf0, qf1;
    { const float* qp = Qh + (qrow + ll) * D + qd * 8; qf0 = cvt8(qp); qf1 = cvt8(qp + 32); }
    floatx4 o[4]; float mi[4], li[4];
#pragma unroll
    for (int dt = 0; dt < 4; ++dt) o[dt] = (floatx4){0.f,0.f,0.f,0.f};
#pragma unroll
    for (int r = 0; r < 4; ++r) { mi[r] = NEG; li[r] = 0.f; }
    const int k_st = tid >> 3, dbase = (tid & 7) * 8;
    const int sq = (dbase >> 3) & 3, sks = dbase >> 5;
    const int kw_slot = (((k_st >> 4) * 2 + sks) * 64)
                      + (((sq << 4) | (k_st & 15)) ^ (sq | (sks << 2)));
    const int kr0 = ln ^ qd, kr1 = ln ^ (qd | 4), vbit3 = (ln >> 3) & 1;
    const int kv_end = qb + 64, wv_end = qrow + 16;
    for (int kv = 0; kv < kv_end; kv += 32) {
        __syncthreads();
        {
            short8 kval = cvt8(Kh + (kv + k_st) * D + dbase);
            ((short8*)lK)[kw_slot] = kval;
            short8 vval = cvt8(Vh + (kv + k_st) * D + dbase);
            const int vq = (k_st >> 3) << 4, vj = k_st & 7;
#pragma unroll
            for (int i = 0; i < 8; ++i) {
                int d = dbase + i, dt = d >> 4, l2 = d & 15;
                int lp = (vq | l2) ^ (((l2 >> 3) & 1) | (dt << 1));
                lV[dt * 512 + lp * 8 + vj] = vval[i];
            }
        }
        __syncthreads();
        if (kv < wv_end) {
            floatx4 sc0 = (floatx4){0.f,0.f,0.f,0.f}, sc1 = sc0; short8 kf;
            kf = ((const short8*)lK)[0*64+kr0]; sc0 = MFMA16(qf0, kf, sc0);
            kf = ((const short8*)lK)[1*64+kr1]; sc0 = MFMA16(qf1, kf, sc0);
            kf = ((const short8*)lK)[2*64+kr0]; sc1 = MFMA16(qf0, kf, sc1);
            kf = ((const short8*)lK)[3*64+kr1]; sc1 = MFMA16(qf1, kf, sc1);
            float p0[4], p1[4]; const int qg = qrow + qd * 4;
#pragma unroll
            for (int r = 0; r < 4; ++r) { p0[r] = sc0[r]*SCL2; p1[r] = sc1[r]*SCL2; }
            if (kv + 31 > qrow) {
                const int k0 = kv + ll, k1 = kv + 16 + ll;
#pragma unroll
                for (int r = 0; r < 4; ++r) {
                    if (k0 > qg + r) p0[r] = NEG;
                    if (k1 > qg + r) p1[r] = NEG;
                }
            }
#pragma unroll
            for (int r = 0; r < 4; ++r) {
                float mx = fmaxf(p0[r], p1[r]);
                mx = fmaxf(mx, __shfl_xor(mx,1)); mx = fmaxf(mx, __shfl_xor(mx,2));
                mx = fmaxf(mx, __shfl_xor(mx,4)); mx = fmaxf(mx, __shfl_xor(mx,8));
                const float nm = fmaxf(mi[r], mx);
                const float a = exp2f(mi[r] - nm); mi[r] = nm;
                p0[r] = exp2f(p0[r] - nm); p1[r] = exp2f(p1[r] - nm);
                float ps = p0[r] + p1[r];
                ps += __shfl_xor(ps,1); ps += __shfl_xor(ps,2);
                ps += __shfl_xor(ps,4); ps += __shfl_xor(ps,8);
                li[r] = li[r] * a + ps;
#pragma unroll
                for (int dt = 0; dt < 4; ++dt) o[dt][r] *= a;
            }
            {
                const int pbase = wv * 512 + (ll & 7);
                const int dl0 = ((ll >> 3) << 4) + qd * 4;
#pragma unroll
                for (int r = 0; r < 4; ++r) {
                    lP[pbase + (dl0 + r) * 8]      = bf16bits(p0[r]);
                    lP[pbase + (dl0 + 32 + r) * 8] = bf16bits(p1[r]);
                }
            }
            __threadfence_block();
            short8 pf = ((const short8*)lP)[wv * 64 + ln];
#pragma unroll
            for (int dt = 0; dt < 4; ++dt) {
                short8 vf = ((const short8*)lV)[dt * 64 + (ln ^ (vbit3 | (dt << 1)))];
                o[dt] = MFMA16(pf, vf, o[dt]);
            }
        }
    }
#pragma unroll
    for (int r = 0; r < 4; ++r) {
        const float rl = 1.f / fmaxf(li[r], 1e-30f);
        const int q = qrow + qd * 4 + r;
        float* op = Og + ((size_t)h * S + q) * D + ll;
#pragma unroll
        for (int dt = 0; dt < 4; ++dt) op[dt * 16] = o[dt][r] * rl;
    }
}

extern "C" void kernel_launch(void* const* d_in, const int* in_sizes, int n_in,
                              void* d_out, int out_size, void* d_ws, size_t ws_size,
                              hipStream_t stream) {
    const float* Q = (const float*)d_in[0];
    const float* K = (const float*)d_in[1];
    const float* V = (const float*)d_in[2];
    float* O = (float*)d_out;
    const size_t elems  = (size_t)16 * 4096 * 64;
    const size_t oneBuf = elems * sizeof(short);          // 8.39 MB
    if (ws_size >= 2 * oneBuf) {
        short* VT  = (short*)d_ws;
        short* K16 = (short*)d_ws + elems;
        prep<<<dim3(1024), dim3(256), 0, stream>>>(V, VT, K, K16, 1);
        attn_fast<true><<<dim3(1024), dim3(256), 0, stream>>>(Q, K, K16, VT, O);
    } else if (ws_size >= oneBuf) {
        short* VT = (short*)d_ws;
        prep<<<dim3(1024), dim3(256), 0, stream>>>(V, VT, K, VT, 0);
        attn_fast<false><<<dim3(1024), dim3(256), 0, stream>>>(Q, K, nullptr, VT, O);
    } else {
        attn_legacy<<<dim3(1024), dim3(256), 0, stream>>>(Q, K, V, O);
    }
}

// Round 9
// 261.464 us; speedup vs baseline: 1.0178x; 1.0178x over previous
//
#include <hip/hip_runtime.h>
#include <hip/hip_bf16.h>

typedef __attribute__((ext_vector_type(8))) short short8;
typedef __attribute__((ext_vector_type(4))) short s4v;
typedef __attribute__((ext_vector_type(4))) int   int4v;
typedef __attribute__((ext_vector_type(4))) float floatx4;

#define MFMA16(A,B,C) __builtin_amdgcn_mfma_f32_16x16x32_bf16(A,B,C,0,0,0)

__device__ __forceinline__ short bf16bits(float x) {
    __hip_bfloat16 h = __float2bfloat16(x);
    return *(short*)&h;
}
__device__ __forceinline__ short8 cvt8(const float* p) {
    floatx4 a = *(const floatx4*)p;
    floatx4 b = *(const floatx4*)(p + 4);
    short8 r;
    r[0]=bf16bits(a.x); r[1]=bf16bits(a.y); r[2]=bf16bits(a.z); r[3]=bf16bits(a.w);
    r[4]=bf16bits(b.x); r[5]=bf16bits(b.y); r[6]=bf16bits(b.z); r[7]=bf16bits(b.w);
    return r;
}
// scaled variant for Q: folds 1/sqrt(d) * log2(e) so softmax is a bare v_exp_f32
__device__ __forceinline__ short8 cvt8s(const float* p) {
    constexpr float SCL2 = 0.125f * 1.44269504088896f;
    floatx4 a = *(const floatx4*)p;
    floatx4 b = *(const floatx4*)(p + 4);
    a *= SCL2; b *= SCL2;
    short8 r;
    r[0]=bf16bits(a.x); r[1]=bf16bits(a.y); r[2]=bf16bits(a.z); r[3]=bf16bits(a.w);
    r[4]=bf16bits(b.x); r[5]=bf16bits(b.y); r[6]=bf16bits(b.z); r[7]=bf16bits(b.w);
    return r;
}
// hardware packed f32->bf16 (RNE, identical rounding to __float2bfloat16)
__device__ __forceinline__ int pk2(float lo, float hi) {
    int r;
    asm("v_cvt_pk_bf16_f32 %0, %1, %2" : "=v"(r) : "v"(lo), "v"(hi));
    return r;
}

// ---- prologue (fused): V -> VT [h][d][s] bf16, and K -> K16 bf16 row-major ----
__global__ __launch_bounds__(256) void prep(const float* __restrict__ V,
                                            short* __restrict__ VT,
                                            const float* __restrict__ K,
                                            short* __restrict__ K16, int doK)
{
    __shared__ short tile[64 * 65];
    const int t  = threadIdx.x;
    const int h  = blockIdx.x >> 6;
    const int s0 = (blockIdx.x & 63) << 6;
    const float* src = V + ((size_t)h * 4096 + s0) * 64;
    const int r = t >> 4, dq = (t & 15) * 4;
#pragma unroll
    for (int pass = 0; pass < 4; ++pass) {
        const int s = pass * 16 + r;
        floatx4 f = *(const floatx4*)(src + s * 64 + dq);
        short* w = tile + s * 65 + dq;
        w[0] = bf16bits(f.x); w[1] = bf16bits(f.y);
        w[2] = bf16bits(f.z); w[3] = bf16bits(f.w);
    }
    __syncthreads();
    const int d = t >> 2, sc = (t & 3) * 16;
    short8 a, b;
#pragma unroll
    for (int j = 0; j < 8; ++j) a[j] = tile[(sc + j) * 65 + d];
#pragma unroll
    for (int j = 0; j < 8; ++j) b[j] = tile[(sc + 8 + j) * 65 + d];
    short* dst = VT + ((size_t)h * 64 + d) * 4096 + s0 + sc;
    *(short8*)dst       = a;
    *(short8*)(dst + 8) = b;
    if (doK) {
        const size_t base = (size_t)blockIdx.x * 4096 + (size_t)t * 16;
        *(short8*)(K16 + base)     = cvt8(K + base);
        *(short8*)(K16 + base + 8) = cvt8(K + base + 8);
    }
}

// ---- main: R6 structure (verified) + R7 register pin (verified) ----
// 4 waves = (qhalf x khalf); 32q/wave (2 groups of 16); khalf waves take the
// even/odd 64-key tile of each 128-key round. Block stages 128 keys/round
// (reg prefetch, 2 barriers) -> barrier pairs per CU halved vs R7 (130 -> ~66).
// Plain-exp softmax => split-K merge is pure addition (through lK/lV scratch).
// amdgpu_waves_per_eu(4,4): pin the allocator at 4 waves/EU (budget 128 VGPR)
// so it cannot chase the 64-reg/8-wave step via scratch spill (R6/R8 bug; the
// (256,4) launch-bounds form only sets a MINIMUM and did not prevent it).
template<bool KB16>
__global__ __attribute__((amdgpu_waves_per_eu(4, 4))) __launch_bounds__(256)
void attn_fast(const float* __restrict__ Qg, const float* __restrict__ Kg,
               const short* __restrict__ K16g, const short* __restrict__ VTg,
               float* __restrict__ Og)
{
    constexpr int S = 4096, D = 64;

    __shared__ __align__(16) short lK[8192];   // 2 x (64 keys x 64 d), swizzled
    __shared__ __align__(16) short lV[8192];   // 2 x (64 d x 64 keys), swizzled

    const int tid = threadIdx.x;
    const int wv  = tid >> 6;        // 0..3
    const int ln  = tid & 63;
    const int ll  = ln & 15;
    const int qd  = ln >> 4;
    const int qhalf = wv & 1;        // which 32 q-rows of the 64-q block tile
    const int khalf = wv >> 1;       // even(0)/odd(1) 64-key tiles

    // balanced qblk mapping: per-CU sets {63-x, 32+x, 31-x, x}
    const int c = blockIdx.x & 255;
    const int s = blockIdx.x >> 8;
    const int h = c & 15;
    const int x = c >> 4;
    const int qblk = (s == 0) ? (63 - x) : (s == 1) ? (32 + x) : (s == 2) ? (31 - x) : x;
    const int qb   = qblk << 6;
    const int qrow = qb + (qhalf << 5);       // wave owns 32 q-rows

    const float* Qh  = Qg  + (size_t)h * S * D;
    const float* Kf  = Kg  + (size_t)h * S * D;
    const short* K16 = K16g + (size_t)h * S * D;
    const short* Vt  = VTg + (size_t)h * 64 * S;

    // Q fragments for both 16-row groups, pre-scaled
    short8 qA0, qA1, qB0, qB1;
    {
        const float* qp = Qh + (qrow + ll) * D + qd * 8;
        qA0 = cvt8s(qp);       qA1 = cvt8s(qp + 32);
        const float* qp2 = qp + 16 * D;
        qB0 = cvt8s(qp2);      qB1 = cvt8s(qp2 + 32);
    }

    floatx4 oA[4], oB[4], olA, olB;
#pragma unroll
    for (int dt = 0; dt < 4; ++dt) { oA[dt] = (floatx4){0.f,0.f,0.f,0.f}; oB[dt] = oA[dt]; }
    olA = (floatx4){0.f,0.f,0.f,0.f};
    olB = olA;

    short8 ones;
#pragma unroll
    for (int j = 0; j < 8; ++j) ones[j] = (short)0x3F80;  // bf16 1.0

    // K staging (R1 pattern): thread t -> key=t>>3 (0..31) per 32-key subtile
    const int kkey = tid >> 3, kd8 = tid & 7;
    const int koct = kd8 & 3;
    short* kdst = lK + ((kkey >> 4) * 2 + (kd8 >> 2)) * 512
                     + ((((kkey & 15) | (koct << 4)) ^ (koct * 5)) * 8);
    const float* ksrcf = Kf  + kkey * 64 + kd8 * 8;
    const short* ksrc6 = K16 + kkey * 64 + kd8 * 8;
    // V staging: thread t -> d=t>>2 (0..63), key-octet=t&3 (from VT)
    const int vd = tid >> 2, voct = tid & 3;
    short* vdst = lV + (vd >> 4) * 512
                     + ((((vd & 15) | (voct << 4)) ^ (voct * 5)) * 8);
    const short* vsrc = Vt + (size_t)vd * S + voct * 8;
    // fragment read block (lK / lV)
    const int rblk = ((ll | (qd << 4)) ^ (qd * 5));

    const int kv_end = qb + 64;          // keys needed by the 64-q block tile
    const int wv_end = qrow + 32;        // this wave's causal limit

    auto ldK = [&](int kv) -> short8 {
        return KB16 ? *(const short8*)(ksrc6 + kv * 64) : cvt8(ksrcf + kv * 64);
    };

    // softmax + in-register P->A-fragment transpose (HW-verified R4):
    // P32(w0,w2), P32(w1,w3), P16(w0,w2), P16(w1,w3)
    auto mkpf = [&](floatx4 sc0, floatx4 sc1, int qgrp, int kvh) -> short8 {
        float p0[4], p1[4];
#pragma unroll
        for (int r = 0; r < 4; ++r) { p0[r] = exp2f(sc0[r]); p1[r] = exp2f(sc1[r]); }
        if (kvh + 31 > qgrp) {                 // diagonal tiles only
            const int qg = qgrp + ll;
            const int k0 = kvh + qd * 4, k1 = k0 + 16;
#pragma unroll
            for (int r = 0; r < 4; ++r) {
                if (k0 + r > qg) p0[r] = 0.f;
                if (k1 + r > qg) p1[r] = 0.f;
            }
        }
        int w0 = pk2(p0[0], p0[1]);
        int w1 = pk2(p0[2], p0[3]);
        int w2 = pk2(p1[0], p1[1]);
        int w3 = pk2(p1[2], p1[3]);
        asm("v_permlane32_swap_b32 %0, %1" : "+v"(w0), "+v"(w2));
        asm("v_permlane32_swap_b32 %0, %1" : "+v"(w1), "+v"(w3));
        asm("v_permlane16_swap_b32 %0, %1" : "+v"(w0), "+v"(w2));
        asm("v_permlane16_swap_b32 %0, %1" : "+v"(w1), "+v"(w3));
        int4v pv = {w0, w1, w2, w3};
        return *(short8*)&pv;
    };

    // ---- preload round 0 (subtiles clamped to stay in-bounds; clamped data
    // lands in the odd tile which is never read when beyond kv_end)
    short8 kp0, kp1, kp2, kp3, vp0, vp1, vp2, vp3;
    {
        const int c2 = (64 < kv_end - 32) ? 64 : kv_end - 32;
        const int c3 = (96 < kv_end - 32) ? 96 : kv_end - 32;
        kp0 = ldK(0);  kp1 = ldK(32);  kp2 = ldK(c2);  kp3 = ldK(c3);
        vp0 = *(const short8*)(vsrc);
        vp1 = *(const short8*)(vsrc + 32);
        vp2 = *(const short8*)(vsrc + c2);
        vp3 = *(const short8*)(vsrc + c3);
    }

    for (int kv2 = 0; kv2 < kv_end; kv2 += 128) {
        __syncthreads();                  // all waves done reading prev round
        *(short8*)(kdst)        = kp0;
        *(short8*)(kdst + 2048) = kp1;
        *(short8*)(kdst + 4096) = kp2;
        *(short8*)(kdst + 6144) = kp3;
        *(short8*)(vdst)        = vp0;
        *(short8*)(vdst + 2048) = vp1;
        *(short8*)(vdst + 4096) = vp2;
        *(short8*)(vdst + 6144) = vp3;
        __syncthreads();                  // staged data visible
        if (kv2 + 128 < kv_end) {         // prefetch next round (in flight
            const int b  = kv2 + 128;     // across the compute below)
            const int c2 = (b + 64 < kv_end - 32) ? b + 64 : kv_end - 32;
            const int c3 = (b + 96 < kv_end - 32) ? b + 96 : kv_end - 32;
            kp0 = ldK(b);  kp1 = ldK(b + 32);  kp2 = ldK(c2);  kp3 = ldK(c3);
            vp0 = *(const short8*)(vsrc + b);
            vp1 = *(const short8*)(vsrc + b + 32);
            vp2 = *(const short8*)(vsrc + c2);
            vp3 = *(const short8*)(vsrc + c3);
        }

        const int kvw = kv2 + (khalf << 6);   // this wave's 64-key tile
        if (kvw < wv_end) {
            const bool h1 = (kvw + 32 < wv_end);
            const short* Kb = lK + (khalf << 12);
            const short* Vb = lV + (khalf << 12);
            // S^T = K Q^T; each kf feeds both q-groups (2x reuse)
            floatx4 zz = (floatx4){0.f,0.f,0.f,0.f};
            floatx4 sA0=zz, sA1=zz, sA2=zz, sA3=zz;
            floatx4 sB0=zz, sB1=zz, sB2=zz, sB3=zz;
            short8 kf;
            __builtin_amdgcn_s_setprio(1);
            kf = ((const short8*)(Kb +    0))[rblk]; sA0 = MFMA16(kf, qA0, sA0); sB0 = MFMA16(kf, qB0, sB0);
            kf = ((const short8*)(Kb +  512))[rblk]; sA0 = MFMA16(kf, qA1, sA0); sB0 = MFMA16(kf, qB1, sB0);
            kf = ((const short8*)(Kb + 1024))[rblk]; sA1 = MFMA16(kf, qA0, sA1); sB1 = MFMA16(kf, qB0, sB1);
            kf = ((const short8*)(Kb + 1536))[rblk]; sA1 = MFMA16(kf, qA1, sA1); sB1 = MFMA16(kf, qB1, sB1);
            if (h1) {
                kf = ((const short8*)(Kb + 2048))[rblk]; sA2 = MFMA16(kf, qA0, sA2); sB2 = MFMA16(kf, qB0, sB2);
                kf = ((const short8*)(Kb + 2560))[rblk]; sA2 = MFMA16(kf, qA1, sA2); sB2 = MFMA16(kf, qB1, sB2);
                kf = ((const short8*)(Kb + 3072))[rblk]; sA3 = MFMA16(kf, qA0, sA3); sB3 = MFMA16(kf, qB0, sB3);
                kf = ((const short8*)(Kb + 3584))[rblk]; sA3 = MFMA16(kf, qA1, sA3); sB3 = MFMA16(kf, qB1, sB3);
            }
            __builtin_amdgcn_s_setprio(0);

            // half 0: softmax -> in-reg P fragments -> PV (vf shared by groups)
            short8 pfA = mkpf(sA0, sA1, qrow,      kvw);
            short8 pfB = mkpf(sB0, sB1, qrow + 16, kvw);
            __builtin_amdgcn_s_setprio(1);
#pragma unroll
            for (int dt = 0; dt < 4; ++dt) {
                short8 vf = ((const short8*)(Vb + dt * 512))[rblk];
                oA[dt] = MFMA16(pfA, vf, oA[dt]);
                oB[dt] = MFMA16(pfB, vf, oB[dt]);
            }
            olA = MFMA16(pfA, ones, olA);
            olB = MFMA16(pfB, ones, olB);
            __builtin_amdgcn_s_setprio(0);
            if (h1) {
                short8 pfA1 = mkpf(sA2, sA3, qrow,      kvw + 32);
                short8 pfB1 = mkpf(sB2, sB3, qrow + 16, kvw + 32);
                __builtin_amdgcn_s_setprio(1);
#pragma unroll
                for (int dt = 0; dt < 4; ++dt) {
                    short8 vf = ((const short8*)(Vb + 2048 + dt * 512))[rblk];
                    oA[dt] = MFMA16(pfA1, vf, oA[dt]);
                    oB[dt] = MFMA16(pfB1, vf, oB[dt]);
                }
                olA = MFMA16(pfA1, ones, olA);
                olB = MFMA16(pfB1, ones, olB);
                __builtin_amdgcn_s_setprio(0);
            }
        }
    }

    // ---- split-K merge: plain-exp softmax => pure addition of O and row-sums.
    // waves 2,3 (khalf=1) publish partials via LDS scratch; waves 0,1 combine.
    __syncthreads();
    float* sAod = (float*)lK;            // 2 x 64 lanes x 20 floats = 10 KB
    float* sBod = (float*)lV;
    const int mbase = ((qhalf << 6) + ln) * 20;
    if (khalf == 1) {
#pragma unroll
        for (int dt = 0; dt < 4; ++dt)
#pragma unroll
            for (int r = 0; r < 4; ++r) {
                sAod[mbase + dt * 4 + r] = oA[dt][r];
                sBod[mbase + dt * 4 + r] = oB[dt][r];
            }
#pragma unroll
        for (int r = 0; r < 4; ++r) {
            sAod[mbase + 16 + r] = olA[r];
            sBod[mbase + 16 + r] = olB[r];
        }
    }
    __syncthreads();
    if (khalf == 0) {
#pragma unroll
        for (int dt = 0; dt < 4; ++dt)
#pragma unroll
            for (int r = 0; r < 4; ++r) {
                oA[dt][r] += sAod[mbase + dt * 4 + r];
                oB[dt][r] += sBod[mbase + dt * 4 + r];
            }
#pragma unroll
        for (int r = 0; r < 4; ++r) {
            olA[r] += sAod[mbase + 16 + r];
            olB[r] += sBod[mbase + 16 + r];
        }
#pragma unroll
        for (int r = 0; r < 4; ++r) {
            const float rl = 1.f / fmaxf(olA[r], 1e-37f);
            const int q = qrow + qd * 4 + r;
            float* op = Og + ((size_t)h * S + q) * D + ll;
#pragma unroll
            for (int dt = 0; dt < 4; ++dt)
                op[dt * 16] = oA[dt][r] * rl;
        }
#pragma unroll
        for (int r = 0; r < 4; ++r) {
            const float rl = 1.f / fmaxf(olB[r], 1e-37f);
            const int q = qrow + 16 + qd * 4 + r;
            float* op = Og + ((size_t)h * S + q) * D + ll;
#pragma unroll
            for (int dt = 0; dt < 4; ++dt)
                op[dt * 16] = oB[dt][r] * rl;
        }
    }
}

// ---- fallback (round-3 verified kernel, no workspace needed) ----
__global__ __launch_bounds__(256, 4)
void attn_legacy(const float* __restrict__ Qg, const float* __restrict__ Kg,
                 const float* __restrict__ Vg, float* __restrict__ Og)
{
    constexpr int S = 4096, D = 64;
    constexpr float SCL2 = 0.125f * 1.44269504088896f;
    constexpr float NEG  = -1.0e30f;
    __shared__ __align__(16) short lK[2048];
    __shared__ __align__(16) short lV[2048];
    __shared__ __align__(16) short lP[2048];
    const int tid = threadIdx.x, wv = tid >> 6, ln = tid & 63, ll = ln & 15, qd = ln >> 4;
    const int bid = blockIdx.x, h = bid & 15, qblk = 63 - (bid >> 4), qb = qblk << 6;
    const float* Qh = Qg + (size_t)h * S * D;
    const float* Kh = Kg + (size_t)h * S * D;
    const float* Vh = Vg + (size_t)h * S * D;
    const int qrow = qb + wv * 16;
    short8 qf0, qf1;
    { const float* qp = Qh + (qrow + ll) * D + qd * 8; qf0 = cvt8(qp); qf1 = cvt8(qp + 32); }
    floatx4 o[4]; float mi[4], li[4];
#pragma unroll
    for (int dt = 0; dt < 4; ++dt) o[dt] = (floatx4){0.f,0.f,0.f,0.f};
#pragma unroll
    for (int r = 0; r < 4; ++r) { mi[r] = NEG; li[r] = 0.f; }
    const int k_st = tid >> 3, dbase = (tid & 7) * 8;
    const int sq = (dbase >> 3) & 3, sks = dbase >> 5;
    const int kw_slot = (((k_st >> 4) * 2 + sks) * 64)
                      + (((sq << 4) | (k_st & 15)) ^ (sq | (sks << 2)));
    const int kr0 = ln ^ qd, kr1 = ln ^ (qd | 4), vbit3 = (ln >> 3) & 1;
    const int kv_end = qb + 64, wv_end = qrow + 16;
    for (int kv = 0; kv < kv_end; kv += 32) {
        __syncthreads();
        {
            short8 kval = cvt8(Kh + (kv + k_st) * D + dbase);
            ((short8*)lK)[kw_slot] = kval;
            short8 vval = cvt8(Vh + (kv + k_st) * D + dbase);
            const int vq = (k_st >> 3) << 4, vj = k_st & 7;
#pragma unroll
            for (int i = 0; i < 8; ++i) {
                int d = dbase + i, dt = d >> 4, l2 = d & 15;
                int lp = (vq | l2) ^ (((l2 >> 3) & 1) | (dt << 1));
                lV[dt * 512 + lp * 8 + vj] = vval[i];
            }
        }
        __syncthreads();
        if (kv < wv_end) {
            floatx4 sc0 = (floatx4){0.f,0.f,0.f,0.f}, sc1 = sc0; short8 kf;
            kf = ((const short8*)lK)[0*64+kr0]; sc0 = MFMA16(qf0, kf, sc0);
            kf = ((const short8*)lK)[1*64+kr1]; sc0 = MFMA16(qf1, kf, sc0);
            kf = ((const short8*)lK)[2*64+kr0]; sc1 = MFMA16(qf0, kf, sc1);
            kf = ((const short8*)lK)[3*64+kr1]; sc1 = MFMA16(qf1, kf, sc1);
            float p0[4], p1[4]; const int qg = qrow + qd * 4;
#pragma unroll
            for (int r = 0; r < 4; ++r) { p0[r] = sc0[r]*SCL2; p1[r] = sc1[r]*SCL2; }
            if (kv + 31 > qrow) {
                const int k0 = kv + ll, k1 = kv + 16 + ll;
#pragma unroll
                for (int r = 0; r < 4; ++r) {
                    if (k0 > qg + r) p0[r] = NEG;
                    if (k1 > qg + r) p1[r] = NEG;
                }
            }
#pragma unroll
            for (int r = 0; r < 4; ++r) {
                float mx = fmaxf(p0[r], p1[r]);
                mx = fmaxf(mx, __shfl_xor(mx,1)); mx = fmaxf(mx, __shfl_xor(mx,2));
                mx = fmaxf(mx, __shfl_xor(mx,4)); mx = fmaxf(mx, __shfl_xor(mx,8));
                const float nm = fmaxf(mi[r], mx);
                const float a = exp2f(mi[r] - nm); mi[r] = nm;
                p0[r] = exp2f(p0[r] - nm); p1[r] = exp2f(p1[r] - nm);
                float ps = p0[r] + p1[r];
                ps += __shfl_xor(ps,1); ps += __shfl_xor(ps,2);
                ps += __shfl_xor(ps,4); ps += __shfl_xor(ps,8);
                li[r] = li[r] * a + ps;
#pragma unroll
                for (int dt = 0; dt < 4; ++dt) o[dt][r] *= a;
            }
            {
                const int pbase = wv * 512 + (ll & 7);
                const int dl0 = ((ll >> 3) << 4) + qd * 4;
#pragma unroll
                for (int r = 0; r < 4; ++r) {
                    lP[pbase + (dl0 + r) * 8]      = bf16bits(p0[r]);
                    lP[pbase + (dl0 + 32 + r) * 8] = bf16bits(p1[r]);
                }
            }
            __threadfence_block();
            short8 pf = ((const short8*)lP)[wv * 64 + ln];
#pragma unroll
            for (int dt = 0; dt < 4; ++dt) {
                short8 vf = ((const short8*)lV)[dt * 64 + (ln ^ (vbit3 | (dt << 1)))];
                o[dt] = MFMA16(pf, vf, o[dt]);
            }
        }
    }
#pragma unroll
    for (int r = 0; r < 4; ++r) {
        const float rl = 1.f / fmaxf(li[r], 1e-30f);
        const int q = qrow + qd * 4 + r;
        float* op = Og + ((size_t)h * S + q) * D + ll;
#pragma unroll
        for (int dt = 0; dt < 4; ++dt) op[dt * 16] = o[dt][r] * rl;
    }
}

extern "C" void kernel_launch(void* const* d_in, const int* in_sizes, int n_in,
                              void* d_out, int out_size, void* d_ws, size_t ws_size,
                              hipStream_t stream) {
    const float* Q = (const float*)d_in[0];
    const float* K = (const float*)d_in[1];
    const float* V = (const float*)d_in[2];
    float* O = (float*)d_out;
    const size_t elems  = (size_t)16 * 4096 * 64;
    const size_t oneBuf = elems * sizeof(short);          // 8.39 MB
    if (ws_size >= 2 * oneBuf) {
        short* VT  = (short*)d_ws;
        short* K16 = (short*)d_ws + elems;
        prep<<<dim3(1024), dim3(256), 0, stream>>>(V, VT, K, K16, 1);
        attn_fast<true><<<dim3(1024), dim3(256), 0, stream>>>(Q, K, K16, VT, O);
    } else if (ws_size >= oneBuf) {
        short* VT = (short*)d_ws;
        prep<<<dim3(1024), dim3(256), 0, stream>>>(V, VT, K, VT, 0);
        attn_fast<false><<<dim3(1024), dim3(256), 0, stream>>>(Q, K, nullptr, VT, O);
    } else {
        attn_legacy<<<dim3(1024), dim3(256), 0, stream>>>(Q, K, V, O);
    }
}

// Round 10
// 184.441 us; speedup vs baseline: 1.4429x; 1.4176x over previous
//
#include <hip/hip_runtime.h>
#include <hip/hip_bf16.h>

typedef __attribute__((ext_vector_type(8))) short short8;
typedef __attribute__((ext_vector_type(4))) short s4v;
typedef __attribute__((ext_vector_type(4))) int   int4v;
typedef __attribute__((ext_vector_type(4))) float floatx4;

#define MFMA16(A,B,C) __builtin_amdgcn_mfma_f32_16x16x32_bf16(A,B,C,0,0,0)

__device__ __forceinline__ short bf16bits(float x) {
    __hip_bfloat16 h = __float2bfloat16(x);
    return *(short*)&h;
}
__device__ __forceinline__ short8 cvt8(const float* p) {
    floatx4 a = *(const floatx4*)p;
    floatx4 b = *(const floatx4*)(p + 4);
    short8 r;
    r[0]=bf16bits(a.x); r[1]=bf16bits(a.y); r[2]=bf16bits(a.z); r[3]=bf16bits(a.w);
    r[4]=bf16bits(b.x); r[5]=bf16bits(b.y); r[6]=bf16bits(b.z); r[7]=bf16bits(b.w);
    return r;
}
// scaled variant for Q: folds 1/sqrt(d) * log2(e) so softmax is a bare v_exp_f32
__device__ __forceinline__ short8 cvt8s(const float* p) {
    constexpr float SCL2 = 0.125f * 1.44269504088896f;
    floatx4 a = *(const floatx4*)p;
    floatx4 b = *(const floatx4*)(p + 4);
    a *= SCL2; b *= SCL2;
    short8 r;
    r[0]=bf16bits(a.x); r[1]=bf16bits(a.y); r[2]=bf16bits(a.z); r[3]=bf16bits(a.w);
    r[4]=bf16bits(b.x); r[5]=bf16bits(b.y); r[6]=bf16bits(b.z); r[7]=bf16bits(b.w);
    return r;
}
// hardware packed f32->bf16 (RNE, identical rounding to __float2bfloat16)
__device__ __forceinline__ int pk2(float lo, float hi) {
    int r;
    asm("v_cvt_pk_bf16_f32 %0, %1, %2" : "=v"(r) : "v"(lo), "v"(hi));
    return r;
}

// ---- prologue (fused): V -> VT [h][d][s] bf16, and K -> K16 bf16 row-major ----
__global__ __launch_bounds__(256) void prep(const float* __restrict__ V,
                                            short* __restrict__ VT,
                                            const float* __restrict__ K,
                                            short* __restrict__ K16, int doK)
{
    __shared__ short tile[64 * 65];
    const int t  = threadIdx.x;
    const int h  = blockIdx.x >> 6;
    const int s0 = (blockIdx.x & 63) << 6;
    const float* src = V + ((size_t)h * 4096 + s0) * 64;
    const int r = t >> 4, dq = (t & 15) * 4;
#pragma unroll
    for (int pass = 0; pass < 4; ++pass) {
        const int s = pass * 16 + r;
        floatx4 f = *(const floatx4*)(src + s * 64 + dq);
        short* w = tile + s * 65 + dq;
        w[0] = bf16bits(f.x); w[1] = bf16bits(f.y);
        w[2] = bf16bits(f.z); w[3] = bf16bits(f.w);
    }
    __syncthreads();
    const int d = t >> 2, sc = (t & 3) * 16;
    short8 a, b;
#pragma unroll
    for (int j = 0; j < 8; ++j) a[j] = tile[(sc + j) * 65 + d];
#pragma unroll
    for (int j = 0; j < 8; ++j) b[j] = tile[(sc + 8 + j) * 65 + d];
    short* dst = VT + ((size_t)h * 64 + d) * 4096 + s0 + sc;
    *(short8*)dst       = a;
    *(short8*)(dst + 8) = b;
    if (doK) {
        const size_t base = (size_t)blockIdx.x * 4096 + (size_t)t * 16;
        *(short8*)(K16 + base)     = cvt8(K + base);
        *(short8*)(K16 + base + 8) = cvt8(K + base + 8);
    }
}

// ---- main: R7 kernel (verified, 73us) + double-buffered LDS pipeline ----
// 4 waves = (qhalf x khalf); 32q/wave (2 groups of 16); khalf waves split each
// 64-key tile into 32-key halves (plain-exp split-K, merge = pure add).
// Software pipeline, ONE barrier per 64-key tile (R7 had two):
//   iter t: barrier; ds_write tile t -> buf[t&1]; prefetch tile t+1 -> regs;
//           compute tile t-1 from buf[(t-1)&1].
// Write-visibility and read-WAR hazards are both one barrier apart. Register
// demand identical to R7 (~60; 4 prefetch short8) -- no spill risk, unlike the
// 128-key structure (R6/R9: allocator pinned 64 VGPR and spilled 150MB).
// LDS 32KB (merge scratch reuses lK/lV) -> 5 blocks/CU.
template<bool KB16>
__global__ __attribute__((amdgpu_waves_per_eu(4, 4))) __launch_bounds__(256)
void attn_fast(const float* __restrict__ Qg, const float* __restrict__ Kg,
               const short* __restrict__ K16g, const short* __restrict__ VTg,
               float* __restrict__ Og)
{
    constexpr int S = 4096, D = 64;

    __shared__ __align__(16) short lK[8192];   // 2 x (64 keys x 64 d), swizzled
    __shared__ __align__(16) short lV[8192];   // 2 x (64 d x 64 keys), swizzled

    const int tid = threadIdx.x;
    const int wv  = tid >> 6;        // 0..3
    const int ln  = tid & 63;
    const int ll  = ln & 15;
    const int qd  = ln >> 4;
    const int qhalf = wv & 1;        // which 32 q-rows of the 64-q block tile
    const int khalf = wv >> 1;       // which 32-key half of each 64-key tile

    // balanced qblk mapping: per-CU sets {63-x, 32+x, 31-x, x}
    const int c = blockIdx.x & 255;
    const int s = blockIdx.x >> 8;
    const int h = c & 15;
    const int x = c >> 4;
    const int qblk = (s == 0) ? (63 - x) : (s == 1) ? (32 + x) : (s == 2) ? (31 - x) : x;
    const int qb   = qblk << 6;
    const int qrow = qb + (qhalf << 5);       // wave owns 32 q-rows

    const float* Qh  = Qg  + (size_t)h * S * D;
    const float* Kf  = Kg  + (size_t)h * S * D;
    const short* K16 = K16g + (size_t)h * S * D;
    const short* Vt  = VTg + (size_t)h * 64 * S;

    // Q fragments for both 16-row groups, pre-scaled
    short8 qA0, qA1, qB0, qB1;
    {
        const float* qp = Qh + (qrow + ll) * D + qd * 8;
        qA0 = cvt8s(qp);       qA1 = cvt8s(qp + 32);
        const float* qp2 = qp + 16 * D;
        qB0 = cvt8s(qp2);      qB1 = cvt8s(qp2 + 32);
    }

    floatx4 oA[4], oB[4], olA, olB;
#pragma unroll
    for (int dt = 0; dt < 4; ++dt) { oA[dt] = (floatx4){0.f,0.f,0.f,0.f}; oB[dt] = oA[dt]; }
    olA = (floatx4){0.f,0.f,0.f,0.f};
    olB = olA;

    short8 ones;
#pragma unroll
    for (int j = 0; j < 8; ++j) ones[j] = (short)0x3F80;  // bf16 1.0

    // K staging (R1/R4 pattern): thread t -> key=t>>3 (0..31) per 32-key subtile
    const int kkey = tid >> 3, kd8 = tid & 7;
    const int koct = kd8 & 3;
    short* kdst = lK + ((kkey >> 4) * 2 + (kd8 >> 2)) * 512
                     + ((((kkey & 15) | (koct << 4)) ^ (koct * 5)) * 8);
    const float* ksrcf = Kf  + kkey * 64 + kd8 * 8;
    const short* ksrc6 = K16 + kkey * 64 + kd8 * 8;
    // V staging: thread t -> d=t>>2 (0..63), key-octet=t&3 (from VT)
    const int vd = tid >> 2, voct = tid & 3;
    short* vdst = lV + (vd >> 4) * 512
                     + ((((vd & 15) | (voct << 4)) ^ (voct * 5)) * 8);
    const short* vsrc = Vt + (size_t)vd * S + voct * 8;
    // fragment read block (lK / lV)
    const int rblk = ((ll | (qd << 4)) ^ (qd * 5));

    const int kv_end = qb + 64;          // keys needed by the 64-q block tile
    const int wv_end = qrow + 32;        // this wave's causal limit

    auto ldK = [&](int kv) -> short8 {
        return KB16 ? *(const short8*)(ksrc6 + kv * 64) : cvt8(ksrcf + kv * 64);
    };

    // softmax + in-register P->A-fragment transpose (HW-verified R4):
    // P32(w0,w2), P32(w1,w3), P16(w0,w2), P16(w1,w3)
    auto mkpf = [&](floatx4 sc0, floatx4 sc1, int qgrp, int kvh) -> short8 {
        float p0[4], p1[4];
#pragma unroll
        for (int r = 0; r < 4; ++r) { p0[r] = exp2f(sc0[r]); p1[r] = exp2f(sc1[r]); }
        if (kvh + 31 > qgrp) {                 // diagonal tiles only
            const int qg = qgrp + ll;
            const int k0 = kvh + qd * 4, k1 = k0 + 16;
#pragma unroll
            for (int r = 0; r < 4; ++r) {
                if (k0 + r > qg) p0[r] = 0.f;
                if (k1 + r > qg) p1[r] = 0.f;
            }
        }
        int w0 = pk2(p0[0], p0[1]);
        int w1 = pk2(p0[2], p0[3]);
        int w2 = pk2(p1[0], p1[1]);
        int w3 = pk2(p1[2], p1[3]);
        asm("v_permlane32_swap_b32 %0, %1" : "+v"(w0), "+v"(w2));
        asm("v_permlane32_swap_b32 %0, %1" : "+v"(w1), "+v"(w3));
        asm("v_permlane16_swap_b32 %0, %1" : "+v"(w0), "+v"(w2));
        asm("v_permlane16_swap_b32 %0, %1" : "+v"(w1), "+v"(w3));
        int4v pv = {w0, w1, w2, w3};
        return *(short8*)&pv;
    };

    short8 kp0 = ldK(0),  kp1 = ldK(32);
    short8 vp0 = *(const short8*)(vsrc);
    short8 vp1 = *(const short8*)(vsrc + 32);

    const int ntiles = kv_end >> 6;
    int bo = 0;                          // buffer written this iteration
    for (int t = 0; t <= ntiles; ++t) {
        // one barrier per tile: makes iter t-1's writes visible AND ensures
        // iter t-1's reads of buf[bo] finished before we overwrite it
        __syncthreads();
        if (t < ntiles) {
            *(short8*)(kdst + bo)        = kp0;
            *(short8*)(kdst + bo + 2048) = kp1;
            *(short8*)(vdst + bo)        = vp0;
            *(short8*)(vdst + bo + 2048) = vp1;
            const int nk = (t + 1) << 6;
            if (nk < kv_end) {           // prefetch tile t+1 (hides under compute)
                kp0 = ldK(nk);
                kp1 = ldK(nk + 32);
                vp0 = *(const short8*)(vsrc + nk);
                vp1 = *(const short8*)(vsrc + nk + 32);
            }
        }
        if (t > 0) {
            const int kv  = (t - 1) << 6;
            const int kvw = kv + (khalf << 5);    // this wave's 32-key half
            if (kvw < wv_end) {
                const int ro = (bo ^ 4096) + (khalf << 11);
                const short* Kb = lK + ro;
                const short* Vb = lV + ro;
                // S^T = K Q^T; each kf feeds both q-groups (2x reuse)
                floatx4 zz = (floatx4){0.f,0.f,0.f,0.f};
                floatx4 sA0=zz, sA1=zz, sB0=zz, sB1=zz;
                short8 kf;
                __builtin_amdgcn_s_setprio(1);
                kf = ((const short8*)(Kb +    0))[rblk]; sA0 = MFMA16(kf, qA0, sA0); sB0 = MFMA16(kf, qB0, sB0);
                kf = ((const short8*)(Kb +  512))[rblk]; sA0 = MFMA16(kf, qA1, sA0); sB0 = MFMA16(kf, qB1, sB0);
                kf = ((const short8*)(Kb + 1024))[rblk]; sA1 = MFMA16(kf, qA0, sA1); sB1 = MFMA16(kf, qB0, sB1);
                kf = ((const short8*)(Kb + 1536))[rblk]; sA1 = MFMA16(kf, qA1, sA1); sB1 = MFMA16(kf, qB1, sB1);
                __builtin_amdgcn_s_setprio(0);

                // softmax -> in-reg P fragments (32 keys each) -> PV
                short8 pfA = mkpf(sA0, sA1, qrow,      kvw);
                short8 pfB = mkpf(sB0, sB1, qrow + 16, kvw);
                __builtin_amdgcn_s_setprio(1);
#pragma unroll
                for (int dt = 0; dt < 4; ++dt) {
                    short8 vf = ((const short8*)(Vb + dt * 512))[rblk];
                    oA[dt] = MFMA16(pfA, vf, oA[dt]);
                    oB[dt] = MFMA16(pfB, vf, oB[dt]);
                }
                olA = MFMA16(pfA, ones, olA);
                olB = MFMA16(pfB, ones, olB);
                __builtin_amdgcn_s_setprio(0);
            }
        }
        bo ^= 4096;
    }

    // ---- split-K merge: plain-exp softmax => pure addition of O and row-sums.
    // khalf=1 waves publish partials via lK/lV scratch; khalf=0 combine + store.
    __syncthreads();
    float* sAod = (float*)lK;            // 2 x 64 lanes x 20 floats = 10 KB
    float* sBod = (float*)lV;
    const int mbase = ((qhalf << 6) + ln) * 20;
    if (khalf == 1) {
#pragma unroll
        for (int dt = 0; dt < 4; ++dt)
#pragma unroll
            for (int r = 0; r < 4; ++r) {
                sAod[mbase + dt * 4 + r] = oA[dt][r];
                sBod[mbase + dt * 4 + r] = oB[dt][r];
            }
#pragma unroll
        for (int r = 0; r < 4; ++r) {
            sAod[mbase + 16 + r] = olA[r];
            sBod[mbase + 16 + r] = olB[r];
        }
    }
    __syncthreads();
    if (khalf == 0) {
#pragma unroll
        for (int dt = 0; dt < 4; ++dt)
#pragma unroll
            for (int r = 0; r < 4; ++r) {
                oA[dt][r] += sAod[mbase + dt * 4 + r];
                oB[dt][r] += sBod[mbase + dt * 4 + r];
            }
#pragma unroll
        for (int r = 0; r < 4; ++r) {
            olA[r] += sAod[mbase + 16 + r];
            olB[r] += sBod[mbase + 16 + r];
        }
#pragma unroll
        for (int r = 0; r < 4; ++r) {
            const float rl = 1.f / fmaxf(olA[r], 1e-37f);
            const int q = qrow + qd * 4 + r;
            float* op = Og + ((size_t)h * S + q) * D + ll;
#pragma unroll
            for (int dt = 0; dt < 4; ++dt)
                op[dt * 16] = oA[dt][r] * rl;
        }
#pragma unroll
        for (int r = 0; r < 4; ++r) {
            const float rl = 1.f / fmaxf(olB[r], 1e-37f);
            const int q = qrow + 16 + qd * 4 + r;
            float* op = Og + ((size_t)h * S + q) * D + ll;
#pragma unroll
            for (int dt = 0; dt < 4; ++dt)
                op[dt * 16] = oB[dt][r] * rl;
        }
    }
}

// ---- fallback (round-3 verified kernel, no workspace needed) ----
__global__ __launch_bounds__(256, 4)
void attn_legacy(const float* __restrict__ Qg, const float* __restrict__ Kg,
                 const float* __restrict__ Vg, float* __restrict__ Og)
{
    constexpr int S = 4096, D = 64;
    constexpr float SCL2 = 0.125f * 1.44269504088896f;
    constexpr float NEG  = -1.0e30f;
    __shared__ __align__(16) short lK[2048];
    __shared__ __align__(16) short lV[2048];
    __shared__ __align__(16) short lP[2048];
    const int tid = threadIdx.x, wv = tid >> 6, ln = tid & 63, ll = ln & 15, qd = ln >> 4;
    const int bid = blockIdx.x, h = bid & 15, qblk = 63 - (bid >> 4), qb = qblk << 6;
    const float* Qh = Qg + (size_t)h * S * D;
    const float* Kh = Kg + (size_t)h * S * D;
    const float* Vh = Vg + (size_t)h * S * D;
    const int qrow = qb + wv * 16;
    short8 qf0, qf1;
    { const float* qp = Qh + (qrow + ll) * D + qd * 8; qf0 = cvt8(qp); qf1 = cvt8(qp + 32); }
    floatx4 o[4]; float mi[4], li[4];
#pragma unroll
    for (int dt = 0; dt < 4; ++dt) o[dt] = (floatx4){0.f,0.f,0.f,0.f};
#pragma unroll
    for (int r = 0; r < 4; ++r) { mi[r] = NEG; li[r] = 0.f; }
    const int k_st = tid >> 3, dbase = (tid & 7) * 8;
    const int sq = (dbase >> 3) & 3, sks = dbase >> 5;
    const int kw_slot = (((k_st >> 4) * 2 + sks) * 64)
                      + (((sq << 4) | (k_st & 15)) ^ (sq | (sks << 2)));
    const int kr0 = ln ^ qd, kr1 = ln ^ (qd | 4), vbit3 = (ln >> 3) & 1;
    const int kv_end = qb + 64, wv_end = qrow + 16;
    for (int kv = 0; kv < kv_end; kv += 32) {
        __syncthreads();
        {
            short8 kval = cvt8(Kh + (kv + k_st) * D + dbase);
            ((short8*)lK)[kw_slot] = kval;
            short8 vval = cvt8(Vh + (kv + k_st) * D + dbase);
            const int vq = (k_st >> 3) << 4, vj = k_st & 7;
#pragma unroll
            for (int i = 0; i < 8; ++i) {
                int d = dbase + i, dt = d >> 4, l2 = d & 15;
                int lp = (vq | l2) ^ (((l2 >> 3) & 1) | (dt << 1));
                lV[dt * 512 + lp * 8 + vj] = vval[i];
            }
        }
        __syncthreads();
        if (kv < wv_end) {
            floatx4 sc0 = (floatx4){0.f,0.f,0.f,0.f}, sc1 = sc0; short8 kf;
            kf = ((const short8*)lK)[0*64+kr0]; sc0 = MFMA16(qf0, kf, sc0);
            kf = ((const short8*)lK)[1*64+kr1]; sc0 = MFMA16(qf1, kf, sc0);
            kf = ((const short8*)lK)[2*64+kr0]; sc1 = MFMA16(qf0, kf, sc1);
            kf = ((const short8*)lK)[3*64+kr1]; sc1 = MFMA16(qf1, kf, sc1);
            float p0[4], p1[4]; const int qg = qrow + qd * 4;
#pragma unroll
            for (int r = 0; r < 4; ++r) { p0[r] = sc0[r]*SCL2; p1[r] = sc1[r]*SCL2; }
            if (kv + 31 > qrow) {
                const int k0 = kv + ll, k1 = kv + 16 + ll;
#pragma unroll
                for (int r = 0; r < 4; ++r) {
                    if (k0 > qg + r) p0[r] = NEG;
                    if (k1 > qg + r) p1[r] = NEG;
                }
            }
#pragma unroll
            for (int r = 0; r < 4; ++r) {
                float mx = fmaxf(p0[r], p1[r]);
                mx = fmaxf(mx, __shfl_xor(mx,1)); mx = fmaxf(mx, __shfl_xor(mx,2));
                mx = fmaxf(mx, __shfl_xor(mx,4)); mx = fmaxf(mx, __shfl_xor(mx,8));
                const float nm = fmaxf(mi[r], mx);
                const float a = exp2f(mi[r] - nm); mi[r] = nm;
                p0[r] = exp2f(p0[r] - nm); p1[r] = exp2f(p1[r] - nm);
                float ps = p0[r] + p1[r];
                ps += __shfl_xor(ps,1); ps += __shfl_xor(ps,2);
                ps += __shfl_xor(ps,4); ps += __shfl_xor(ps,8);
                li[r] = li[r] * a + ps;
#pragma unroll
                for (int dt = 0; dt < 4; ++dt) o[dt][r] *= a;
            }
            {
                const int pbase = wv * 512 + (ll & 7);
                const int dl0 = ((ll >> 3) << 4) + qd * 4;
#pragma unroll
                for (int r = 0; r < 4; ++r) {
                    lP[pbase + (dl0 + r) * 8]      = bf16bits(p0[r]);
                    lP[pbase + (dl0 + 32 + r) * 8] = bf16bits(p1[r]);
                }
            }
            __threadfence_block();
            short8 pf = ((const short8*)lP)[wv * 64 + ln];
#pragma unroll
            for (int dt = 0; dt < 4; ++dt) {
                short8 vf = ((const short8*)lV)[dt * 64 + (ln ^ (vbit3 | (dt << 1)))];
                o[dt] = MFMA16(pf, vf, o[dt]);
            }
        }
    }
#pragma unroll
    for (int r = 0; r < 4; ++r) {
        const float rl = 1.f / fmaxf(li[r], 1e-30f);
        const int q = qrow + qd * 4 + r;
        float* op = Og + ((size_t)h * S + q) * D + ll;
#pragma unroll
        for (int dt = 0; dt < 4; ++dt) op[dt * 16] = o[dt][r] * rl;
    }
}

extern "C" void kernel_launch(void* const* d_in, const int* in_sizes, int n_in,
                              void* d_out, int out_size, void* d_ws, size_t ws_size,
                              hipStream_t stream) {
    const float* Q = (const float*)d_in[0];
    const float* K = (const float*)d_in[1];
    const float* V = (const float*)d_in[2];
    float* O = (float*)d_out;
    const size_t elems  = (size_t)16 * 4096 * 64;
    const size_t oneBuf = elems * sizeof(short);          // 8.39 MB
    if (ws_size >= 2 * oneBuf) {
        short* VT  = (short*)d_ws;
        short* K16 = (short*)d_ws + elems;
        prep<<<dim3(1024), dim3(256), 0, stream>>>(V, VT, K, K16, 1);
        attn_fast<true><<<dim3(1024), dim3(256), 0, stream>>>(Q, K, K16, VT, O);
    } else if (ws_size >= oneBuf) {
        short* VT = (short*)d_ws;
        prep<<<dim3(1024), dim3(256), 0, stream>>>(V, VT, K, VT, 0);
        attn_fast<false><<<dim3(1024), dim3(256), 0, stream>>>(Q, K, nullptr, VT, O);
    } else {
        attn_legacy<<<dim3(1024), dim3(256), 0, stream>>>(Q, K, V, O);
    }
}